// Round 17
// baseline (197.949 us; speedup 1.0000x reference)
//
#include <hip/hip_runtime.h>
#include <math.h>

namespace {

constexpr int RAD  = 6;
constexpr int P    = 13;
constexpr int NWIN = 169;   // P*P
constexpr int NTOT = 338;   // 2 refs * NWIN
constexpr int NCH  = 128;
constexpr int NCLS = 32;
constexpr int W    = 64;
constexpr int HW   = 4096;
constexpr float FOUR_LN2 = 2.772588722239781f;

// ---- kernel A tiling (R15 traffic/schedule; 8px-per-thread compute) ----
constexpr int TX    = 32;            // pixels per block (half row)
constexpr int CHUNK = 8;             // channels per stage
constexpr int PW    = 48;            // patch width: 44 used + 4 pad
constexpr int PR    = 13;            // patch rows (dy)
constexpr int FRELEMS = CHUNK * PR * PW;   // 4992
constexpr int NLD   = 20;            // ceil(4992/256)
constexpr int NCHUNK = NCH / CHUNK;  // 16
constexpr int TILE  = TX * NWIN;     // 5408 floats
constexpr size_t VOLF = (size_t)2 * HW * NTOT;  // floats in volume

__device__ __forceinline__ bool better(float va, int ia, float vb, int ib) {
  return (va > vb) || ((va == vb) && (ia < ib));
}

// ================= Kernel A: correlation volume =================
// 512 blocks, 256 threads, XCD swizzle (R15-proven). Compute threads:
// (x-oct 0..3, dy 0..12) = 52 per channel-group, 8 px each, acc[13][8].
__global__ __launch_bounds__(256, 2) void corr_kernel(
    const float* __restrict__ fr,   // [2][2][128][64][64]  (nref,b,c,y,x)
    const float* __restrict__ ft,   // [2][128][64][64]
    float* __restrict__ vol,
    const int* __restrict__ q,
    int* __restrict__ lab) {
  const int blk = blockIdx.x;
  const int t  = threadIdx.x;

  // ---- folded label map ----
  if (blk < 64) {
    const int idx = blk * 256 + t;
    const int i2b = idx >> 12;
    const int rem = idx & 4095;
    const int y2  = rem >> 6;
    const int x2  = rem & 63;
    lab[idx] = q[(size_t)i2b * 65536 + (y2 * 4) * 256 + x2 * 4];
  }

  // ---- XCD-locality swizzle (bijective: 512 = 8 * 64) ----
  const int lb = (blk & 7) * 64 + (blk >> 3);
  const int xh = lb & 1;
  const int y  = (lb >> 1) & 63;
  const int bi = lb >> 7;              // b*2+i
  const int b  = bi >> 1;
  const int ii = bi & 1;
  const int x0 = xh * TX;
  const int cg = t >> 7;               // channel group 0/1
  const int tl = t & 127;

  __shared__ __align__(16) float smem[2 * FRELEMS];     // 39936 B
  __shared__ __align__(16) float ftbuf[2][CHUNK * TX];  // 2048 B

  const int xg = tl & 3;               // x-oct (8 px)
  const int dy = tl >> 2;              // 0..12 valid when tl<52
  const bool comp = (tl < 52);

  const float* frbase = fr + (size_t)((ii * 2 + b) * NCH) * HW;
  const float* ftp = ft + (size_t)(b * NCH + (t >> 5)) * HW + y * W + x0 + (t & 31);

  // ---- hoisted staging offsets (u16-packed) ----
  unsigned offp[10];
  unsigned vmsk = 0u;
  #pragma unroll
  for (int u = 0; u < NLD; ++u) {
    const int e = t + u * 256;
    unsigned o = 0;
    if (e < FRELEMS) {
      const int cc  = e / (PR * PW);
      const int rem = e - cc * (PR * PW);
      const int r   = rem / PW;
      const int xc  = rem - r * PW;
      const int yy  = y + r - RAD;
      const int xx  = x0 - RAD + xc;
      if ((unsigned)yy < 64u && (unsigned)xx < 64u && xc < 44) {
        o = (unsigned)(cc * HW + yy * W + xx);   // < 32768
        vmsk |= (1u << u);
      }
    }
    if (u & 1) offp[u >> 1] |= (o << 16); else offp[u >> 1] = o;
  }

  // ---- pre-zero LDS (thread t zeroes slots t+256u; buf-1 writes land in
  //      other threads' slots but the prologue barrier orders them) ----
  for (int e = t; e < 2 * FRELEMS; e += 256) smem[e] = 0.f;

  float acc[13][8];
  #pragma unroll
  for (int dx = 0; dx < 13; ++dx)
    #pragma unroll
    for (int px = 0; px < 8; ++px) acc[dx][px] = 0.f;

  float rg[NLD];
  float rft;

  auto stage_load = [&](int c0) {
    const float* fb = frbase + (size_t)c0 * HW;
    #pragma unroll
    for (int u = 0; u < NLD; ++u) {
      if (vmsk & (1u << u)) {
        const int o = (u & 1) ? (int)(offp[u >> 1] >> 16) : (int)(offp[u >> 1] & 0xffffu);
        rg[u] = fb[o];
      }
    }
    rft = ftp[(size_t)c0 * HW];
  };
  auto stage_write = [&](int s) {
    float* frb = smem + s * FRELEMS;
    #pragma unroll
    for (int u = 0; u < NLD; ++u)
      if (vmsk & (1u << u)) frb[t + u * 256] = rg[u];
    ftbuf[s][t] = rft;
  };

  stage_load(0);
  stage_write(0);
  __syncthreads();

  for (int k = 0; k < NCHUNK; ++k) {
    const int cur = k & 1;
    if (k < NCHUNK - 1) stage_load((k + 1) * CHUNK);
    if (comp) {
      const float* frb = smem + cur * FRELEMS;
      #pragma unroll
      for (int c2 = 0; c2 < 4; ++c2) {
        const int cc = cg * 4 + c2;
        const float* fp = frb + (cc * PR + dy) * PW + xg * 8;   // 32B aligned
        float w[20];
        #pragma unroll
        for (int j = 0; j < 5; ++j) {
          const float4 q4 = *(const float4*)(fp + 4 * j);
          w[4 * j] = q4.x; w[4 * j + 1] = q4.y; w[4 * j + 2] = q4.z; w[4 * j + 3] = q4.w;
        }
        const float4 ta = *(const float4*)(&ftbuf[cur][cc * TX + xg * 8]);
        const float4 tb = *(const float4*)(&ftbuf[cur][cc * TX + xg * 8 + 4]);
        const float tq8[8] = {ta.x, ta.y, ta.z, ta.w, tb.x, tb.y, tb.z, tb.w};
        #pragma unroll
        for (int dx = 0; dx < 13; ++dx)
          #pragma unroll
          for (int px = 0; px < 8; ++px)
            acc[dx][px] = fmaf(w[dx + px], tq8[px], acc[dx][px]);
      }
    }
    // R9/R15-proven single-barrier double-buffer schedule.
    if (k < NCHUNK - 1) stage_write(cur ^ 1);
    __syncthreads();
  }

  // --- cross-cg reduction (staging LDS dead; 52x104 = 5408 floats) ---
  if (comp && cg == 1) {
    float* rb = smem + tl * 104;
    #pragma unroll
    for (int dx = 0; dx < 13; ++dx) {
      *(float4*)(rb + dx * 8)     = make_float4(acc[dx][0], acc[dx][1], acc[dx][2], acc[dx][3]);
      *(float4*)(rb + dx * 8 + 4) = make_float4(acc[dx][4], acc[dx][5], acc[dx][6], acc[dx][7]);
    }
  }
  __syncthreads();
  if (comp && cg == 0) {
    const float* rb = smem + tl * 104;
    #pragma unroll
    for (int dx = 0; dx < 13; ++dx) {
      const float4 r0 = *(const float4*)(rb + dx * 8);
      const float4 r1 = *(const float4*)(rb + dx * 8 + 4);
      acc[dx][0] += r0.x; acc[dx][1] += r0.y; acc[dx][2] += r0.z; acc[dx][3] += r0.w;
      acc[dx][4] += r1.x; acc[dx][5] += r1.y; acc[dx][6] += r1.z; acc[dx][7] += r1.w;
    }
  }
  __syncthreads();
  // --- transpose to tile[px][m] ---
  if (comp && cg == 0) {
    #pragma unroll
    for (int px = 0; px < 8; ++px)
      #pragma unroll
      for (int dx = 0; dx < 13; ++dx)
        smem[(xg * 8 + px) * NWIN + dy * 13 + dx] = acc[dx][px];
  }
  __syncthreads();
  {
    float* gb = vol + ((size_t)(b * HW + y * W + x0) * 2 + ii) * NWIN;
    for (int u = 0; u < 22; ++u) {
      const int e = t + u * 256;
      if (e < TILE) {
        const int xl2 = e / NWIN;
        const int mm  = e - xl2 * NWIN;
        gb[(size_t)xl2 * (2 * NWIN) + mm] = smem[e];
      }
    }
  }
}

// ================= Kernel B: wave-per-pixel post-processing =================
__global__ __launch_bounds__(256) void post_kernel(
    const float* __restrict__ vol,  // [pix][2][169]
    const int*  __restrict__ lab,   // [4][64][64]
    float* __restrict__ out) {      // [2][32][64][64]
  const int blk  = blockIdx.x;
  const int t    = threadIdx.x;
  const int w    = t >> 6;
  const int lane = t & 63;
  const int pix  = blk * 4 + w;
  const int b = pix >> 12;
  const int y = (pix >> 6) & 63;
  const int x = pix & 63;

  __shared__ float accS[4][NCLS];
  accS[w][lane & 31] = 0.f;

  float vv[6];
  float lmax = -INFINITY;
  const float* vp = vol + (size_t)pix * NTOT;
  #pragma unroll
  for (int k = 0; k < 6; ++k) {
    const int e = lane + 64 * k;
    vv[k] = (e < NTOT) ? vp[e] : -INFINITY;
    lmax = fmaxf(lmax, vv[k]);
  }
  #pragma unroll
  for (int off = 32; off > 0; off >>= 1)
    lmax = fmaxf(lmax, __shfl_xor(lmax, off));

  float p[6];
  float lsum = 0.f;
  #pragma unroll
  for (int k = 0; k < 6; ++k) {
    const int e = lane + 64 * k;
    p[k] = (e < NTOT) ? __expf(vv[k] - lmax) : 0.f;
    lsum += p[k];
  }
  #pragma unroll
  for (int off = 32; off > 0; off >>= 1)
    lsum += __shfl_xor(lsum, off);
  const float rinv = 1.f / lsum;
  #pragma unroll
  for (int k = 0; k < 6; ++k) p[k] *= rinv;

  float a1_0 = -1.f, a2_0 = -1.f, a1_1 = -1.f, a2_1 = -1.f;
  int   j1_0 = 1 << 20, j2_0 = 1 << 20, j1_1 = 1 << 20, j2_1 = 1 << 20;
  #pragma unroll
  for (int k = 0; k < 6; ++k) {
    const int e = lane + 64 * k;
    if (e < NTOT) {
      const int r = (e >= NWIN) ? 1 : 0;
      const int m = e - r * NWIN;
      const float pv = p[k];
      if (r == 0) {
        if (better(pv, m, a1_0, j1_0)) { a2_0 = a1_0; j2_0 = j1_0; a1_0 = pv; j1_0 = m; }
        else if (better(pv, m, a2_0, j2_0)) { a2_0 = pv; j2_0 = m; }
      } else {
        if (better(pv, m, a1_1, j1_1)) { a2_1 = a1_1; j2_1 = j1_1; a1_1 = pv; j1_1 = m; }
        else if (better(pv, m, a2_1, j2_1)) { a2_1 = pv; j2_1 = m; }
      }
    }
  }
  #pragma unroll
  for (int off = 32; off > 0; off >>= 1) {
    {
      const float u1 = __shfl_xor(a1_0, off); const int q1 = __shfl_xor(j1_0, off);
      const float u2 = __shfl_xor(a2_0, off); const int q2 = __shfl_xor(j2_0, off);
      if (better(u1, q1, a1_0, j1_0)) {
        float nv2; int ni2;
        if (better(a1_0, j1_0, u2, q2)) { nv2 = a1_0; ni2 = j1_0; }
        else                            { nv2 = u2;   ni2 = q2; }
        a1_0 = u1; j1_0 = q1; a2_0 = nv2; j2_0 = ni2;
      } else if (better(u1, q1, a2_0, j2_0)) { a2_0 = u1; j2_0 = q1; }
    }
    {
      const float u1 = __shfl_xor(a1_1, off); const int q1 = __shfl_xor(j1_1, off);
      const float u2 = __shfl_xor(a2_1, off); const int q2 = __shfl_xor(j2_1, off);
      if (better(u1, q1, a1_1, j1_1)) {
        float nv2; int ni2;
        if (better(a1_1, j1_1, u2, q2)) { nv2 = a1_1; ni2 = j1_1; }
        else                            { nv2 = u2;   ni2 = q2; }
        a1_1 = u1; j1_1 = q1; a2_1 = nv2; j2_1 = ni2;
      } else if (better(u1, q1, a2_1, j2_1)) { a2_1 = u1; j2_1 = q1; }
    }
  }

  const float e10 = __expf(a1_0), e20 = __expf(a2_0);
  const float rs0 = 1.f / (e10 + e20);
  const float w00 = e10 * rs0, w10 = e20 * rs0;
  const bool  fl0 = (a1_0 > 0.1f);
  const float xs00 = (float)(j1_0 % P), ys00 = (float)(j1_0 / P);
  const float xs10 = (float)(j2_0 % P), ys10 = (float)(j2_0 / P);

  const float e11 = __expf(a1_1), e21 = __expf(a2_1);
  const float rs1 = 1.f / (e11 + e21);
  const float w01 = e11 * rs1, w11 = e21 * rs1;
  const bool  fl1 = (a1_1 > 0.1f);
  const float xs01 = (float)(j1_1 % P), ys01 = (float)(j1_1 / P);
  const float xs11 = (float)(j2_1 % P), ys11 = (float)(j2_1 / P);

  #pragma unroll
  for (int k = 0; k < 6; ++k) {
    const int e = lane + 64 * k;
    if (e < NTOT) {
      const int r  = (e >= NWIN) ? 1 : 0;
      const int m  = e - r * NWIN;
      const int dy = m / P;
      const int dx = m - dy * P;
      const bool  fl = r ? fl1 : fl0;
      float val;
      if (fl) {
        const float wA = r ? w01 : w00, wB = r ? w11 : w10;
        const float xA = r ? xs01 : xs00, yA = r ? ys01 : ys00;
        const float xB = r ? xs11 : xs10, yB = r ? ys11 : ys10;
        const float fdx0 = (float)dx - xA, fdy0 = (float)dy - yA;
        const float fdx1 = (float)dx - xB, fdy1 = (float)dy - yB;
        val = wA * __expf(-FOUR_LN2 * (fdx0 * fdx0 + fdy0 * fdy0))
            + wB * __expf(-FOUR_LN2 * (fdx1 * fdx1 + fdy1 * fdy1));
      } else {
        val = p[k];
      }
      const int yy = y + dy - RAD;
      const int xx = x + dx - RAD;
      if ((unsigned)yy < 64u && (unsigned)xx < 64u) {
        const int cls = lab[(size_t)(r * 2 + b) * 4096 + yy * W + xx];
        atomicAdd(&accS[w][cls], val);
      }
    }
  }
  __syncthreads();

  if (t < 4 * NCLS) {
    const int cls = t >> 2;
    const int j   = t & 3;
    const int x0  = (blk * 4) & 63;
    const float sc = (cls == 0) ? 1.0f : 1.15f;
    out[(size_t)(b * NCLS + cls) * HW + y * W + x0 + j] = accS[j][cls] * sc;
  }
}

}  // namespace

extern "C" void kernel_launch(void* const* d_in, const int* in_sizes, int n_in,
                              void* d_out, int out_size, void* d_ws, size_t ws_size,
                              hipStream_t stream) {
  const float* fr = (const float*)d_in[0];   // feats_r
  const float* ft = (const float*)d_in[1];   // feats_t
  const int*   q  = (const int*)d_in[2];     // quantized_r
  float* out = (float*)d_out;
  float* vol = (float*)d_ws;                                   // 11,075,584 B
  int*   lab = (int*)((char*)d_ws + VOLF * sizeof(float));     // +64 KB

  corr_kernel<<<dim3(2 * 2 * 64 * 2), dim3(256), 0, stream>>>(fr, ft, vol, q, lab);
  post_kernel<<<dim3(2 * HW / 4), dim3(256), 0, stream>>>(vol, lab, out);
}

// Round 18
// 80.986 us; speedup vs baseline: 2.4442x; 2.4442x over previous
//
#include <hip/hip_runtime.h>
#include <math.h>

namespace {

constexpr int RAD  = 6;
constexpr int P    = 13;
constexpr int NWIN = 169;   // P*P
constexpr int NTOT = 338;   // 2 refs * NWIN
constexpr int NCH  = 128;
constexpr int NCLS = 32;
constexpr int W    = 64;
constexpr int HW   = 4096;
constexpr float FOUR_LN2 = 2.772588722239781f;

// ---- kernel A tiling (R15-proven geometry & traffic) ----
constexpr int TX    = 32;            // pixels per block (half row)
constexpr int CHUNK = 8;             // channels per stage
constexpr int PW    = 48;            // patch width: 44 used + 4 pad
constexpr int PR    = 13;            // patch rows (dy)
constexpr int FRELEMS = CHUNK * PR * PW;   // 4992
constexpr int NLD   = 20;            // ceil(4992/256)
constexpr int NCHUNK = NCH / CHUNK;  // 16
constexpr int TILE  = TX * NWIN;     // 5408 floats
constexpr size_t VOLF = (size_t)2 * HW * NTOT;  // floats in volume

__device__ __forceinline__ bool better(float va, int ia, float vb, int ib) {
  return (va > vb) || ((va == vb) && (ia < ib));
}

// ================= Kernel A: correlation volume =================
// 512 blocks, 256 threads, XCD swizzle. R15 dataflow + 2-deep register
// pipeline with STATICALLY-NAMED reg sets (rgA/rgB) via manual 2x unroll.
__global__ __launch_bounds__(256, 2) void corr_kernel(
    const float* __restrict__ fr,   // [2][2][128][64][64]  (nref,b,c,y,x)
    const float* __restrict__ ft,   // [2][128][64][64]
    float* __restrict__ vol,
    const int* __restrict__ q,
    int* __restrict__ lab) {
  const int blk = blockIdx.x;
  const int t  = threadIdx.x;

  // ---- folded label map ----
  if (blk < 64) {
    const int idx = blk * 256 + t;
    const int i2b = idx >> 12;
    const int rem = idx & 4095;
    const int y2  = rem >> 6;
    const int x2  = rem & 63;
    lab[idx] = q[(size_t)i2b * 65536 + (y2 * 4) * 256 + x2 * 4];
  }

  // ---- XCD-locality swizzle (bijective: 512 = 8 * 64) ----
  const int lb = (blk & 7) * 64 + (blk >> 3);
  const int xh = lb & 1;
  const int y  = (lb >> 1) & 63;
  const int bi = lb >> 7;              // b*2+i
  const int b  = bi >> 1;
  const int ii = bi & 1;
  const int x0 = xh * TX;
  const int cg = t >> 7;               // channel group 0/1
  const int tl = t & 127;

  __shared__ __align__(16) float smem[2 * FRELEMS];     // 39936 B
  __shared__ __align__(16) float ftbuf[2][CHUNK * TX];  // 2048 B

  const int xg = tl & 7;               // x-quad within half row
  const int dy = tl >> 3;              // 0..12 valid when tl<104
  const bool comp = (tl < 104);

  const float* frbase = fr + (size_t)((ii * 2 + b) * NCH) * HW;
  const float* ftp = ft + (size_t)(b * NCH + (t >> 5)) * HW + y * W + x0 + (t & 31);

  // ---- hoisted staging offsets (loop-invariant across chunks) ----
  int offc[NLD];
  unsigned vmsk = 0u;
  #pragma unroll
  for (int u = 0; u < NLD; ++u) {
    const int e = t + u * 256;
    int o = 0;
    if (e < FRELEMS) {
      const int cc  = e / (PR * PW);
      const int rem = e - cc * (PR * PW);
      const int r   = rem / PW;
      const int xc  = rem - r * PW;
      const int yy  = y + r - RAD;
      const int xx  = x0 - RAD + xc;
      if ((unsigned)yy < 64u && (unsigned)xx < 64u && xc < 44) {
        o = cc * HW + yy * W + xx;
        vmsk |= (1u << u);
      }
    }
    offc[u] = o;
  }

  float acc[13][4];
  #pragma unroll
  for (int dx = 0; dx < 13; ++dx)
    #pragma unroll
    for (int k = 0; k < 4; ++k) acc[dx][k] = 0.f;

  float rgA[NLD], rgB[NLD];
  float rftA, rftB;

  auto stage_loadA = [&](int c0) {
    const float* fb = frbase + (size_t)c0 * HW;
    #pragma unroll
    for (int u = 0; u < NLD; ++u) {
      const float v = fb[offc[u]];
      rgA[u] = (vmsk & (1u << u)) ? v : 0.f;
    }
    rftA = ftp[(size_t)c0 * HW];
  };
  auto stage_loadB = [&](int c0) {
    const float* fb = frbase + (size_t)c0 * HW;
    #pragma unroll
    for (int u = 0; u < NLD; ++u) {
      const float v = fb[offc[u]];
      rgB[u] = (vmsk & (1u << u)) ? v : 0.f;
    }
    rftB = ftp[(size_t)c0 * HW];
  };
  auto stage_writeA = [&](int s) {
    float* frb = smem + s * FRELEMS;
    #pragma unroll
    for (int u = 0; u < NLD; ++u) {
      const int e = t + u * 256;
      if (e < FRELEMS) frb[e] = rgA[u];
    }
    ftbuf[s][t] = rftA;
  };
  auto stage_writeB = [&](int s) {
    float* frb = smem + s * FRELEMS;
    #pragma unroll
    for (int u = 0; u < NLD; ++u) {
      const int e = t + u * 256;
      if (e < FRELEMS) frb[e] = rgB[u];
    }
    ftbuf[s][t] = rftB;
  };

  auto compute = [&](int buf) {
    if (comp) {
      const float* frb = smem + buf * FRELEMS;
      #pragma unroll
      for (int c2 = 0; c2 < 4; ++c2) {
        const int cc = cg * 4 + c2;
        const float* fp = frb + (cc * PR + dy) * PW + xg * 4;
        float w[16];
        #pragma unroll
        for (int j = 0; j < 4; ++j) {
          const float4 q4 = *(const float4*)(fp + 4 * j);
          w[4 * j] = q4.x; w[4 * j + 1] = q4.y; w[4 * j + 2] = q4.z; w[4 * j + 3] = q4.w;
        }
        const float4 tq = *(const float4*)(&ftbuf[buf][cc * TX + xg * 4]);
        const float tqa[4] = {tq.x, tq.y, tq.z, tq.w};
        #pragma unroll
        for (int dx = 0; dx < 13; ++dx)
          #pragma unroll
          for (int kk = 0; kk < 4; ++kk)
            acc[dx][kk] = fmaf(w[dx + kk], tqa[kk], acc[dx][kk]);
      }
    }
  };

  // ---- prologue: c0 staged in buf0; c1 loads in flight in rgB ----
  stage_loadA(0);
  stage_writeA(0);
  stage_loadB(CHUNK);
  __syncthreads();

  // ---- 2-deep pipelined main loop (manual 2x unroll, static reg sets) ----
  // even k: loadA(c[k+2]) | compute(buf0 = c[k]) | writeB(buf1 = c[k+1])
  // odd  k: loadB(c[k+2]) | compute(buf1 = c[k]) | writeA(buf0 = c[k+1])
  // Hazards: buf written one barrier after its last reader; rgX reloaded
  // only after its writeX. Load->write distance = 2 chunk periods.
  #pragma unroll
  for (int k = 0; k < NCHUNK; k += 2) {
    // even iteration
    if (k + 2 < NCHUNK) stage_loadA((k + 2) * CHUNK);
    compute(0);
    if (k + 1 < NCHUNK) stage_writeB(1);
    __syncthreads();
    // odd iteration
    if (k + 3 < NCHUNK) stage_loadB((k + 3) * CHUNK);
    compute(1);
    if (k + 2 < NCHUNK) stage_writeA(0);
    __syncthreads();
  }

  // --- cross-cg reduction (staging buffers dead now) ---
  if (comp && cg == 1) {
    float* rb = smem + tl * 52;
    #pragma unroll
    for (int dx = 0; dx < 13; ++dx)
      *(float4*)(rb + dx * 4) = make_float4(acc[dx][0], acc[dx][1], acc[dx][2], acc[dx][3]);
  }
  __syncthreads();
  if (comp && cg == 0) {
    const float* rb = smem + tl * 52;
    #pragma unroll
    for (int dx = 0; dx < 13; ++dx) {
      const float4 r = *(const float4*)(rb + dx * 4);
      acc[dx][0] += r.x; acc[dx][1] += r.y; acc[dx][2] += r.z; acc[dx][3] += r.w;
    }
  }
  __syncthreads();
  if (comp && cg == 0) {
    #pragma unroll
    for (int dx = 0; dx < 13; ++dx)
      #pragma unroll
      for (int kk = 0; kk < 4; ++kk)
        smem[(xg * 4 + kk) * NWIN + dy * 13 + dx] = acc[dx][kk];
  }
  __syncthreads();
  {
    float* gb = vol + ((size_t)(b * HW + y * W + x0) * 2 + ii) * NWIN;
    for (int u = 0; u < 22; ++u) {
      const int e = t + u * 256;
      if (e < TILE) {
        const int xl2 = e / NWIN;
        const int mm  = e - xl2 * NWIN;
        gb[(size_t)xl2 * (2 * NWIN) + mm] = smem[e];
      }
    }
  }
}

// ================= Kernel B: wave-per-pixel post-processing =================
__global__ __launch_bounds__(256) void post_kernel(
    const float* __restrict__ vol,  // [pix][2][169]
    const int*  __restrict__ lab,   // [4][64][64]
    float* __restrict__ out) {      // [2][32][64][64]
  const int blk  = blockIdx.x;
  const int t    = threadIdx.x;
  const int w    = t >> 6;
  const int lane = t & 63;
  const int pix  = blk * 4 + w;
  const int b = pix >> 12;
  const int y = (pix >> 6) & 63;
  const int x = pix & 63;

  __shared__ float accS[4][NCLS];
  accS[w][lane & 31] = 0.f;

  float vv[6];
  float lmax = -INFINITY;
  const float* vp = vol + (size_t)pix * NTOT;
  #pragma unroll
  for (int k = 0; k < 6; ++k) {
    const int e = lane + 64 * k;
    vv[k] = (e < NTOT) ? vp[e] : -INFINITY;
    lmax = fmaxf(lmax, vv[k]);
  }
  #pragma unroll
  for (int off = 32; off > 0; off >>= 1)
    lmax = fmaxf(lmax, __shfl_xor(lmax, off));

  float p[6];
  float lsum = 0.f;
  #pragma unroll
  for (int k = 0; k < 6; ++k) {
    const int e = lane + 64 * k;
    p[k] = (e < NTOT) ? __expf(vv[k] - lmax) : 0.f;
    lsum += p[k];
  }
  #pragma unroll
  for (int off = 32; off > 0; off >>= 1)
    lsum += __shfl_xor(lsum, off);
  const float rinv = 1.f / lsum;
  #pragma unroll
  for (int k = 0; k < 6; ++k) p[k] *= rinv;

  float a1_0 = -1.f, a2_0 = -1.f, a1_1 = -1.f, a2_1 = -1.f;
  int   j1_0 = 1 << 20, j2_0 = 1 << 20, j1_1 = 1 << 20, j2_1 = 1 << 20;
  #pragma unroll
  for (int k = 0; k < 6; ++k) {
    const int e = lane + 64 * k;
    if (e < NTOT) {
      const int r = (e >= NWIN) ? 1 : 0;
      const int m = e - r * NWIN;
      const float pv = p[k];
      if (r == 0) {
        if (better(pv, m, a1_0, j1_0)) { a2_0 = a1_0; j2_0 = j1_0; a1_0 = pv; j1_0 = m; }
        else if (better(pv, m, a2_0, j2_0)) { a2_0 = pv; j2_0 = m; }
      } else {
        if (better(pv, m, a1_1, j1_1)) { a2_1 = a1_1; j2_1 = j1_1; a1_1 = pv; j1_1 = m; }
        else if (better(pv, m, a2_1, j2_1)) { a2_1 = pv; j2_1 = m; }
      }
    }
  }
  #pragma unroll
  for (int off = 32; off > 0; off >>= 1) {
    {
      const float u1 = __shfl_xor(a1_0, off); const int q1 = __shfl_xor(j1_0, off);
      const float u2 = __shfl_xor(a2_0, off); const int q2 = __shfl_xor(j2_0, off);
      if (better(u1, q1, a1_0, j1_0)) {
        float nv2; int ni2;
        if (better(a1_0, j1_0, u2, q2)) { nv2 = a1_0; ni2 = j1_0; }
        else                            { nv2 = u2;   ni2 = q2; }
        a1_0 = u1; j1_0 = q1; a2_0 = nv2; j2_0 = ni2;
      } else if (better(u1, q1, a2_0, j2_0)) { a2_0 = u1; j2_0 = q1; }
    }
    {
      const float u1 = __shfl_xor(a1_1, off); const int q1 = __shfl_xor(j1_1, off);
      const float u2 = __shfl_xor(a2_1, off); const int q2 = __shfl_xor(j2_1, off);
      if (better(u1, q1, a1_1, j1_1)) {
        float nv2; int ni2;
        if (better(a1_1, j1_1, u2, q2)) { nv2 = a1_1; ni2 = j1_1; }
        else                            { nv2 = u2;   ni2 = q2; }
        a1_1 = u1; j1_1 = q1; a2_1 = nv2; j2_1 = ni2;
      } else if (better(u1, q1, a2_1, j2_1)) { a2_1 = u1; j2_1 = q1; }
    }
  }

  const float e10 = __expf(a1_0), e20 = __expf(a2_0);
  const float rs0 = 1.f / (e10 + e20);
  const float w00 = e10 * rs0, w10 = e20 * rs0;
  const bool  fl0 = (a1_0 > 0.1f);
  const float xs00 = (float)(j1_0 % P), ys00 = (float)(j1_0 / P);
  const float xs10 = (float)(j2_0 % P), ys10 = (float)(j2_0 / P);

  const float e11 = __expf(a1_1), e21 = __expf(a2_1);
  const float rs1 = 1.f / (e11 + e21);
  const float w01 = e11 * rs1, w11 = e21 * rs1;
  const bool  fl1 = (a1_1 > 0.1f);
  const float xs01 = (float)(j1_1 % P), ys01 = (float)(j1_1 / P);
  const float xs11 = (float)(j2_1 % P), ys11 = (float)(j2_1 / P);

  #pragma unroll
  for (int k = 0; k < 6; ++k) {
    const int e = lane + 64 * k;
    if (e < NTOT) {
      const int r  = (e >= NWIN) ? 1 : 0;
      const int m  = e - r * NWIN;
      const int dy = m / P;
      const int dx = m - dy * P;
      const bool  fl = r ? fl1 : fl0;
      float val;
      if (fl) {
        const float wA = r ? w01 : w00, wB = r ? w11 : w10;
        const float xA = r ? xs01 : xs00, yA = r ? ys01 : ys00;
        const float xB = r ? xs11 : xs10, yB = r ? ys11 : ys10;
        const float fdx0 = (float)dx - xA, fdy0 = (float)dy - yA;
        const float fdx1 = (float)dx - xB, fdy1 = (float)dy - yB;
        val = wA * __expf(-FOUR_LN2 * (fdx0 * fdx0 + fdy0 * fdy0))
            + wB * __expf(-FOUR_LN2 * (fdx1 * fdx1 + fdy1 * fdy1));
      } else {
        val = p[k];
      }
      const int yy = y + dy - RAD;
      const int xx = x + dx - RAD;
      if ((unsigned)yy < 64u && (unsigned)xx < 64u) {
        const int cls = lab[(size_t)(r * 2 + b) * 4096 + yy * W + xx];
        atomicAdd(&accS[w][cls], val);
      }
    }
  }
  __syncthreads();

  if (t < 4 * NCLS) {
    const int cls = t >> 2;
    const int j   = t & 3;
    const int x0  = (blk * 4) & 63;
    const float sc = (cls == 0) ? 1.0f : 1.15f;
    out[(size_t)(b * NCLS + cls) * HW + y * W + x0 + j] = accS[j][cls] * sc;
  }
}

}  // namespace

extern "C" void kernel_launch(void* const* d_in, const int* in_sizes, int n_in,
                              void* d_out, int out_size, void* d_ws, size_t ws_size,
                              hipStream_t stream) {
  const float* fr = (const float*)d_in[0];   // feats_r
  const float* ft = (const float*)d_in[1];   // feats_t
  const int*   q  = (const int*)d_in[2];     // quantized_r
  float* out = (float*)d_out;
  float* vol = (float*)d_ws;                                   // 11,075,584 B
  int*   lab = (int*)((char*)d_ws + VOLF * sizeof(float));     // +64 KB

  corr_kernel<<<dim3(2 * 2 * 64 * 2), dim3(256), 0, stream>>>(fr, ft, vol, q, lab);
  post_kernel<<<dim3(2 * HW / 4), dim3(256), 0, stream>>>(vol, lab, out);
}

// Round 19
// 66.470 us; speedup vs baseline: 2.9780x; 1.2184x over previous
//
#include <hip/hip_runtime.h>
#include <math.h>

namespace {

constexpr int RAD  = 6;
constexpr int P    = 13;
constexpr int NWIN = 169;   // P*P
constexpr int NTOT = 338;   // 2 refs * NWIN
constexpr int NCH  = 128;
constexpr int NCLS = 32;
constexpr int W    = 64;
constexpr int HW   = 4096;
constexpr float FOUR_LN2 = 2.772588722239781f;

// ---- kernel A tiling: dy-split (R16-proven) + CHUNK=16 (8 chunks) ----
constexpr int TX    = 32;            // pixels per block (half row)
constexpr int CHUNK = 16;            // channels per stage -> 8 chunks
constexpr int PW    = 48;            // patch width: 44 used + 4 pad
constexpr int FRMAX = CHUNK * 7 * PW;      // 5376 floats (h=0 size)
constexpr int NLD   = 21;            // ceil(5376/256)
constexpr int NCHUNK = NCH / CHUNK;  // 8
constexpr size_t VOLF = (size_t)2 * HW * NTOT;  // floats in volume

__device__ __forceinline__ bool better(float va, int ia, float vb, int ib) {
  return (va > vb) || ((va == vb) && (ia < ib));
}

// ================= Kernel A: correlation volume =================
// 1024 blocks, 256 threads, 3 blocks/CU (LDS 47KB), VGPR ~85 (<128 cap).
// XCD swizzle: XCD k (= blk%8) gets lb in [k*128,(k+1)*128) = one (ref,b)
// x 32 consecutive y x both xh x both h. First 64 blocks build label map.
__global__ __launch_bounds__(256, 4) void corr_kernel(
    const float* __restrict__ fr,   // [2][2][128][64][64]  (nref,b,c,y,x)
    const float* __restrict__ ft,   // [2][128][64][64]
    float* __restrict__ vol,
    const int* __restrict__ q,
    int* __restrict__ lab) {
  const int blk = blockIdx.x;
  const int t  = threadIdx.x;

  if (blk < 64) {
    const int idx = blk * 256 + t;
    const int i2b = idx >> 12;
    const int rem = idx & 4095;
    const int y2  = rem >> 6;
    const int x2  = rem & 63;
    lab[idx] = q[(size_t)i2b * 65536 + (y2 * 4) * 256 + x2 * 4];
  }

  // ---- XCD-locality swizzle (bijective: 1024 = 8 * 128) ----
  const int lb = (blk & 7) * 128 + (blk >> 3);
  const int h  = lb & 1;               // dy-half
  const int xh = (lb >> 1) & 1;
  const int y  = (lb >> 2) & 63;
  const int bi = lb >> 8;              // b*2+i
  const int b  = bi >> 1;
  const int ii = bi & 1;
  const int x0 = xh * TX;
  const int cg = t >> 7;               // channel group 0/1
  const int tl = t & 127;

  const int RH    = 7 - h;             // staged rows: 7 (h=0) / 6 (h=1)
  const int yb    = h ? (y + 1) : (y - 6);   // first staged row (logical)
  const int m0    = h * 91;            // m-offset of this half (7*13)
  const int frele = CHUNK * RH * PW;   // 5376 / 4608
  const int msz   = RH * P;            // 91 / 78 outputs per pixel

  __shared__ __align__(16) float smem[2 * FRMAX];       // 43008 B
  __shared__ __align__(16) float ftbuf[2][CHUNK * TX];  // 4096 B

  const int xp  = tl & 15;             // x-pair (2 px)
  const int dyl = tl >> 4;             // 0..7; valid when < RH
  const bool comp = (dyl < RH);

  const float* frbase = fr + (size_t)((ii * 2 + b) * NCH) * HW;
  // ft: thread stages elements t (ch t>>5) and t+256 (ch 8+(t>>5))
  const float* ftp = ft + (size_t)(b * NCH + (t >> 5)) * HW + y * W + x0 + (t & 31);

  // ---- hoisted staging offsets ----
  int offc[NLD];
  unsigned vmsk = 0u;
  #pragma unroll
  for (int u = 0; u < NLD; ++u) {
    const int e = t + u * 256;
    int o = 0;
    if (e < frele) {
      const int cc  = e / (RH * PW);
      const int rem = e - cc * (RH * PW);
      const int r   = rem / PW;
      const int xc  = rem - r * PW;
      const int yy  = yb + r;
      const int xx  = x0 - RAD + xc;
      if ((unsigned)yy < 64u && (unsigned)xx < 64u && xc < 44) {
        o = cc * HW + yy * W + xx;
        vmsk |= (1u << u);
      }
    }
    offc[u] = o;
  }

  float acc[13][2];
  #pragma unroll
  for (int dx = 0; dx < 13; ++dx) { acc[dx][0] = 0.f; acc[dx][1] = 0.f; }

  float rg[NLD];
  float rft0, rft1;

  auto stage_load = [&](int c0) {
    const float* fb = frbase + (size_t)c0 * HW;
    #pragma unroll
    for (int u = 0; u < NLD; ++u) {
      const float v = fb[offc[u]];
      rg[u] = (vmsk & (1u << u)) ? v : 0.f;
    }
    rft0 = ftp[(size_t)c0 * HW];
    rft1 = ftp[(size_t)(c0 + 8) * HW];
  };
  auto stage_write = [&](int s) {
    float* frb = smem + s * FRMAX;
    #pragma unroll
    for (int u = 0; u < NLD; ++u) {
      const int e = t + u * 256;
      if (e < frele) frb[e] = rg[u];
    }
    ftbuf[s][t]       = rft0;
    ftbuf[s][t + 256] = rft1;
  };

  stage_load(0);
  stage_write(0);
  __syncthreads();

  for (int k = 0; k < NCHUNK; ++k) {
    const int cur = k & 1;
    if (k < NCHUNK - 1) stage_load((k + 1) * CHUNK);
    if (comp) {
      const float* frb = smem + cur * FRMAX;
      #pragma unroll
      for (int c2 = 0; c2 < 8; ++c2) {
        const int cc = cg * 8 + c2;
        const float* fp = frb + (cc * RH + dyl) * PW + xp * 2;
        float w[14];
        #pragma unroll
        for (int j = 0; j < 14; ++j) w[j] = fp[j];
        const float2 tq = *(const float2*)(&ftbuf[cur][cc * TX + xp * 2]);
        #pragma unroll
        for (int dx = 0; dx < 13; ++dx) {
          acc[dx][0] = fmaf(w[dx    ], tq.x, acc[dx][0]);
          acc[dx][1] = fmaf(w[dx + 1], tq.y, acc[dx][1]);
        }
      }
    }
    // R9/R16-proven single-barrier double-buffer schedule.
    if (k < NCHUNK - 1) stage_write(cur ^ 1);
    __syncthreads();
  }

  // --- cross-cg reduction (staging LDS dead) ---
  if (comp && cg == 1) {
    float* rb = smem + tl * 26;
    #pragma unroll
    for (int dx = 0; dx < 13; ++dx) {
      rb[dx * 2]     = acc[dx][0];
      rb[dx * 2 + 1] = acc[dx][1];
    }
  }
  __syncthreads();
  if (comp && cg == 0) {
    const float* rb = smem + tl * 26;
    #pragma unroll
    for (int dx = 0; dx < 13; ++dx) {
      acc[dx][0] += rb[dx * 2];
      acc[dx][1] += rb[dx * 2 + 1];
    }
  }
  __syncthreads();
  // --- transpose to tile[px][m_local] ---
  if (comp && cg == 0) {
    #pragma unroll
    for (int dx = 0; dx < 13; ++dx) {
      smem[(xp * 2    ) * msz + dyl * P + dx] = acc[dx][0];
      smem[(xp * 2 + 1) * msz + dyl * P + dx] = acc[dx][1];
    }
  }
  __syncthreads();
  // --- store: 32 runs of msz consecutive floats ---
  {
    const int tot = TX * msz;
    float* gb = vol + ((size_t)(b * HW + y * W + x0) * 2 + ii) * NWIN + m0;
    for (int e = t; e < tot; e += 256) {
      const int px = e / msz;
      const int m  = e - px * msz;
      gb[(size_t)px * (2 * NWIN) + m] = smem[e];
    }
  }
}

// ================= Kernel B: wave-per-pixel post-processing =================
__global__ __launch_bounds__(256) void post_kernel(
    const float* __restrict__ vol,  // [pix][2][169]
    const int*  __restrict__ lab,   // [4][64][64]
    float* __restrict__ out) {      // [2][32][64][64]
  const int blk  = blockIdx.x;
  const int t    = threadIdx.x;
  const int w    = t >> 6;
  const int lane = t & 63;
  const int pix  = blk * 4 + w;
  const int b = pix >> 12;
  const int y = (pix >> 6) & 63;
  const int x = pix & 63;

  __shared__ float accS[4][NCLS];
  accS[w][lane & 31] = 0.f;

  float vv[6];
  float lmax = -INFINITY;
  const float* vp = vol + (size_t)pix * NTOT;
  #pragma unroll
  for (int k = 0; k < 6; ++k) {
    const int e = lane + 64 * k;
    vv[k] = (e < NTOT) ? vp[e] : -INFINITY;
    lmax = fmaxf(lmax, vv[k]);
  }
  #pragma unroll
  for (int off = 32; off > 0; off >>= 1)
    lmax = fmaxf(lmax, __shfl_xor(lmax, off));

  float p[6];
  float lsum = 0.f;
  #pragma unroll
  for (int k = 0; k < 6; ++k) {
    const int e = lane + 64 * k;
    p[k] = (e < NTOT) ? __expf(vv[k] - lmax) : 0.f;
    lsum += p[k];
  }
  #pragma unroll
  for (int off = 32; off > 0; off >>= 1)
    lsum += __shfl_xor(lsum, off);
  const float rinv = 1.f / lsum;
  #pragma unroll
  for (int k = 0; k < 6; ++k) p[k] *= rinv;

  float a1_0 = -1.f, a2_0 = -1.f, a1_1 = -1.f, a2_1 = -1.f;
  int   j1_0 = 1 << 20, j2_0 = 1 << 20, j1_1 = 1 << 20, j2_1 = 1 << 20;
  #pragma unroll
  for (int k = 0; k < 6; ++k) {
    const int e = lane + 64 * k;
    if (e < NTOT) {
      const int r = (e >= NWIN) ? 1 : 0;
      const int m = e - r * NWIN;
      const float pv = p[k];
      if (r == 0) {
        if (better(pv, m, a1_0, j1_0)) { a2_0 = a1_0; j2_0 = j1_0; a1_0 = pv; j1_0 = m; }
        else if (better(pv, m, a2_0, j2_0)) { a2_0 = pv; j2_0 = m; }
      } else {
        if (better(pv, m, a1_1, j1_1)) { a2_1 = a1_1; j2_1 = j1_1; a1_1 = pv; j1_1 = m; }
        else if (better(pv, m, a2_1, j2_1)) { a2_1 = pv; j2_1 = m; }
      }
    }
  }
  #pragma unroll
  for (int off = 32; off > 0; off >>= 1) {
    {
      const float u1 = __shfl_xor(a1_0, off); const int q1 = __shfl_xor(j1_0, off);
      const float u2 = __shfl_xor(a2_0, off); const int q2 = __shfl_xor(j2_0, off);
      if (better(u1, q1, a1_0, j1_0)) {
        float nv2; int ni2;
        if (better(a1_0, j1_0, u2, q2)) { nv2 = a1_0; ni2 = j1_0; }
        else                            { nv2 = u2;   ni2 = q2; }
        a1_0 = u1; j1_0 = q1; a2_0 = nv2; j2_0 = ni2;
      } else if (better(u1, q1, a2_0, j2_0)) { a2_0 = u1; j2_0 = q1; }
    }
    {
      const float u1 = __shfl_xor(a1_1, off); const int q1 = __shfl_xor(j1_1, off);
      const float u2 = __shfl_xor(a2_1, off); const int q2 = __shfl_xor(j2_1, off);
      if (better(u1, q1, a1_1, j1_1)) {
        float nv2; int ni2;
        if (better(a1_1, j1_1, u2, q2)) { nv2 = a1_1; ni2 = j1_1; }
        else                            { nv2 = u2;   ni2 = q2; }
        a1_1 = u1; j1_1 = q1; a2_1 = nv2; j2_1 = ni2;
      } else if (better(u1, q1, a2_1, j2_1)) { a2_1 = u1; j2_1 = q1; }
    }
  }

  const float e10 = __expf(a1_0), e20 = __expf(a2_0);
  const float rs0 = 1.f / (e10 + e20);
  const float w00 = e10 * rs0, w10 = e20 * rs0;
  const bool  fl0 = (a1_0 > 0.1f);
  const float xs00 = (float)(j1_0 % P), ys00 = (float)(j1_0 / P);
  const float xs10 = (float)(j2_0 % P), ys10 = (float)(j2_0 / P);

  const float e11 = __expf(a1_1), e21 = __expf(a2_1);
  const float rs1 = 1.f / (e11 + e21);
  const float w01 = e11 * rs1, w11 = e21 * rs1;
  const bool  fl1 = (a1_1 > 0.1f);
  const float xs01 = (float)(j1_1 % P), ys01 = (float)(j1_1 / P);
  const float xs11 = (float)(j2_1 % P), ys11 = (float)(j2_1 / P);

  #pragma unroll
  for (int k = 0; k < 6; ++k) {
    const int e = lane + 64 * k;
    if (e < NTOT) {
      const int r  = (e >= NWIN) ? 1 : 0;
      const int m  = e - r * NWIN;
      const int dy = m / P;
      const int dx = m - dy * P;
      const bool  fl = r ? fl1 : fl0;
      float val;
      if (fl) {
        const float wA = r ? w01 : w00, wB = r ? w11 : w10;
        const float xA = r ? xs01 : xs00, yA = r ? ys01 : ys00;
        const float xB = r ? xs11 : xs10, yB = r ? ys11 : ys10;
        const float fdx0 = (float)dx - xA, fdy0 = (float)dy - yA;
        const float fdx1 = (float)dx - xB, fdy1 = (float)dy - yB;
        val = wA * __expf(-FOUR_LN2 * (fdx0 * fdx0 + fdy0 * fdy0))
            + wB * __expf(-FOUR_LN2 * (fdx1 * fdx1 + fdy1 * fdy1));
      } else {
        val = p[k];
      }
      const int yy = y + dy - RAD;
      const int xx = x + dx - RAD;
      if ((unsigned)yy < 64u && (unsigned)xx < 64u) {
        const int cls = lab[(size_t)(r * 2 + b) * 4096 + yy * W + xx];
        atomicAdd(&accS[w][cls], val);
      }
    }
  }
  __syncthreads();

  if (t < 4 * NCLS) {
    const int cls = t >> 2;
    const int j   = t & 3;
    const int x0  = (blk * 4) & 63;
    const float sc = (cls == 0) ? 1.0f : 1.15f;
    out[(size_t)(b * NCLS + cls) * HW + y * W + x0 + j] = accS[j][cls] * sc;
  }
}

}  // namespace

extern "C" void kernel_launch(void* const* d_in, const int* in_sizes, int n_in,
                              void* d_out, int out_size, void* d_ws, size_t ws_size,
                              hipStream_t stream) {
  const float* fr = (const float*)d_in[0];   // feats_r
  const float* ft = (const float*)d_in[1];   // feats_t
  const int*   q  = (const int*)d_in[2];     // quantized_r
  float* out = (float*)d_out;
  float* vol = (float*)d_ws;                                   // 11,075,584 B
  int*   lab = (int*)((char*)d_ws + VOLF * sizeof(float));     // +64 KB

  corr_kernel<<<dim3(2 * 2 * 64 * 2 * 2), dim3(256), 0, stream>>>(fr, ft, vol, q, lab);
  post_kernel<<<dim3(2 * HW / 4), dim3(256), 0, stream>>>(vol, lab, out);
}

// Round 20
// 58.858 us; speedup vs baseline: 3.3631x; 1.1293x over previous
//
#include <hip/hip_runtime.h>
#include <math.h>

namespace {

constexpr int RAD  = 6;
constexpr int P    = 13;
constexpr int NWIN = 169;   // P*P
constexpr int NTOT = 338;   // 2 refs * NWIN
constexpr int NCH  = 128;
constexpr int NCLS = 32;
constexpr int W    = 64;
constexpr int HW   = 4096;
constexpr float FOUR_LN2 = 2.772588722239781f;

// ---- kernel A tiling (R9-proven geometry & traffic; R15 swizzle) ----
constexpr int TX    = 32;            // pixels per block (half row)
constexpr int CHUNK = 8;             // channels per stage (U-shape optimum)
constexpr int PW    = 48;            // patch width: 44 used + 4 pad
constexpr int PR    = 13;            // patch rows (dy)
constexpr int FRELEMS = CHUNK * PR * PW;   // 4992
constexpr int NLD   = 20;            // ceil(4992/256)
constexpr int NCHUNK = NCH / CHUNK;  // 16
constexpr int TILE  = TX * NWIN;     // 5408 floats
constexpr size_t VOLF = (size_t)2 * HW * NTOT;  // floats in volume

__device__ __forceinline__ bool better(float va, int ia, float vb, int ib) {
  return (va > vb) || ((va == vb) && (ia < ib));
}

// ================= Kernel A: correlation volume =================
// 512 blocks, 256 threads. XCD-aware swizzle: XCD k (= blk%8, round-robin
// dispatch) gets the contiguous logical slice [k*64,(k+1)*64) = one (ref,b)
// tensor x half the y range -> fr working set ~1.4MB fits the 4MB XCD L2.
// First 64 blocks also build the label map (folded lab_kernel).
__global__ __launch_bounds__(256, 2) void corr_kernel(
    const float* __restrict__ fr,   // [2][2][128][64][64]  (nref,b,c,y,x)
    const float* __restrict__ ft,   // [2][128][64][64]
    float* __restrict__ vol,
    const int* __restrict__ q,
    int* __restrict__ lab) {
  const int blk = blockIdx.x;
  const int t  = threadIdx.x;

  // ---- folded label map (64 blocks x 256 threads = 16384 elements) ----
  if (blk < 64) {
    const int idx = blk * 256 + t;
    const int i2b = idx >> 12;
    const int rem = idx & 4095;
    const int y2  = rem >> 6;
    const int x2  = rem & 63;
    lab[idx] = q[(size_t)i2b * 65536 + (y2 * 4) * 256 + x2 * 4];
  }

  // ---- XCD-locality swizzle (bijective: 512 = 8 * 64) ----
  const int lb = (blk & 7) * 64 + (blk >> 3);
  const int xh = lb & 1;
  const int y  = (lb >> 1) & 63;
  const int bi = lb >> 7;              // b*2+i
  const int b  = bi >> 1;
  const int ii = bi & 1;
  const int x0 = xh * TX;
  const int cg = t >> 7;               // channel group 0/1
  const int tl = t & 127;

  __shared__ __align__(16) float smem[2 * FRELEMS];     // 39936 B
  __shared__ __align__(16) float ftbuf[2][CHUNK * TX];  // 2048 B

  const int xg = tl & 7;               // x-quad within half row
  const int dy = tl >> 3;              // 0..12 valid when tl<104
  const bool comp = (tl < 104);

  // fr outer layout is [nref][b] -> index ii*2+b
  const float* frbase = fr + (size_t)((ii * 2 + b) * NCH) * HW;
  const float* ftp = ft + (size_t)(b * NCH + (t >> 5)) * HW + y * W + x0 + (t & 31);

  // ---- hoisted staging offsets (loop-invariant across chunks) ----
  int offc[NLD];
  unsigned vmsk = 0u;
  #pragma unroll
  for (int u = 0; u < NLD; ++u) {
    const int e = t + u * 256;
    int o = 0;
    if (e < FRELEMS) {
      const int cc  = e / (PR * PW);
      const int rem = e - cc * (PR * PW);
      const int r   = rem / PW;
      const int xc  = rem - r * PW;
      const int yy  = y + r - RAD;
      const int xx  = x0 - RAD + xc;
      if ((unsigned)yy < 64u && (unsigned)xx < 64u && xc < 44) {
        o = cc * HW + yy * W + xx;
        vmsk |= (1u << u);
      }
    }
    offc[u] = o;
  }

  float acc[13][4];
  #pragma unroll
  for (int dx = 0; dx < 13; ++dx)
    #pragma unroll
    for (int k = 0; k < 4; ++k) acc[dx][k] = 0.f;

  float rg[NLD];
  float rft;

  auto stage_load = [&](int c0) {
    const float* fb = frbase + (size_t)c0 * HW;
    #pragma unroll
    for (int u = 0; u < NLD; ++u) {
      const float v = fb[offc[u]];
      rg[u] = (vmsk & (1u << u)) ? v : 0.f;
    }
    rft = ftp[(size_t)c0 * HW];
  };
  auto stage_write = [&](int s) {
    float* frb = smem + s * FRELEMS;
    #pragma unroll
    for (int u = 0; u < NLD; ++u) {
      const int e = t + u * 256;
      if (e < FRELEMS) frb[e] = rg[u];
    }
    ftbuf[s][t] = rft;
  };

  stage_load(0);
  stage_write(0);
  __syncthreads();

  for (int k = 0; k < NCHUNK; ++k) {
    const int cur = k & 1;
    if (k < NCHUNK - 1) stage_load((k + 1) * CHUNK);
    if (comp) {
      const float* frb = smem + cur * FRELEMS;
      #pragma unroll
      for (int c2 = 0; c2 < 4; ++c2) {
        const int cc = cg * 4 + c2;
        const float* fp = frb + (cc * PR + dy) * PW + xg * 4;
        float w[16];
        #pragma unroll
        for (int j = 0; j < 4; ++j) {
          const float4 q4 = *(const float4*)(fp + 4 * j);
          w[4 * j] = q4.x; w[4 * j + 1] = q4.y; w[4 * j + 2] = q4.z; w[4 * j + 3] = q4.w;
        }
        const float4 tq = *(const float4*)(&ftbuf[cur][cc * TX + xg * 4]);
        const float tqa[4] = {tq.x, tq.y, tq.z, tq.w};
        #pragma unroll
        for (int dx = 0; dx < 13; ++dx)
          #pragma unroll
          for (int kk = 0; kk < 4; ++kk)
            acc[dx][kk] = fmaf(w[dx + kk], tqa[kk], acc[dx][kk]);
      }
    }
    // R9-proven single-barrier double-buffer schedule.
    if (k < NCHUNK - 1) stage_write(cur ^ 1);
    __syncthreads();
  }

  // --- cross-cg reduction (staging buffers dead now) ---
  if (comp && cg == 1) {
    float* rb = smem + tl * 52;
    #pragma unroll
    for (int dx = 0; dx < 13; ++dx)
      *(float4*)(rb + dx * 4) = make_float4(acc[dx][0], acc[dx][1], acc[dx][2], acc[dx][3]);
  }
  __syncthreads();
  if (comp && cg == 0) {
    const float* rb = smem + tl * 52;
    #pragma unroll
    for (int dx = 0; dx < 13; ++dx) {
      const float4 r = *(const float4*)(rb + dx * 4);
      acc[dx][0] += r.x; acc[dx][1] += r.y; acc[dx][2] += r.z; acc[dx][3] += r.w;
    }
  }
  __syncthreads();
  if (comp && cg == 0) {
    #pragma unroll
    for (int dx = 0; dx < 13; ++dx)
      #pragma unroll
      for (int kk = 0; kk < 4; ++kk)
        smem[(xg * 4 + kk) * NWIN + dy * 13 + dx] = acc[dx][kk];
  }
  __syncthreads();
  {
    float* gb = vol + ((size_t)(b * HW + y * W + x0) * 2 + ii) * NWIN;
    for (int u = 0; u < 22; ++u) {
      const int e = t + u * 256;
      if (e < TILE) {
        const int xl2 = e / NWIN;
        const int mm  = e - xl2 * NWIN;
        gb[(size_t)xl2 * (2 * NWIN) + mm] = smem[e];
      }
    }
  }
}

// ================= Kernel B: wave-per-pixel post-processing =================
__global__ __launch_bounds__(256) void post_kernel(
    const float* __restrict__ vol,  // [pix][2][169]
    const int*  __restrict__ lab,   // [4][64][64]
    float* __restrict__ out) {      // [2][32][64][64]
  const int blk  = blockIdx.x;
  const int t    = threadIdx.x;
  const int w    = t >> 6;
  const int lane = t & 63;
  const int pix  = blk * 4 + w;
  const int b = pix >> 12;
  const int y = (pix >> 6) & 63;
  const int x = pix & 63;

  __shared__ float accS[4][NCLS];
  accS[w][lane & 31] = 0.f;

  float vv[6];
  float lmax = -INFINITY;
  const float* vp = vol + (size_t)pix * NTOT;
  #pragma unroll
  for (int k = 0; k < 6; ++k) {
    const int e = lane + 64 * k;
    vv[k] = (e < NTOT) ? vp[e] : -INFINITY;
    lmax = fmaxf(lmax, vv[k]);
  }
  #pragma unroll
  for (int off = 32; off > 0; off >>= 1)
    lmax = fmaxf(lmax, __shfl_xor(lmax, off));

  float p[6];
  float lsum = 0.f;
  #pragma unroll
  for (int k = 0; k < 6; ++k) {
    const int e = lane + 64 * k;
    p[k] = (e < NTOT) ? __expf(vv[k] - lmax) : 0.f;
    lsum += p[k];
  }
  #pragma unroll
  for (int off = 32; off > 0; off >>= 1)
    lsum += __shfl_xor(lsum, off);
  const float rinv = 1.f / lsum;
  #pragma unroll
  for (int k = 0; k < 6; ++k) p[k] *= rinv;

  float a1_0 = -1.f, a2_0 = -1.f, a1_1 = -1.f, a2_1 = -1.f;
  int   j1_0 = 1 << 20, j2_0 = 1 << 20, j1_1 = 1 << 20, j2_1 = 1 << 20;
  #pragma unroll
  for (int k = 0; k < 6; ++k) {
    const int e = lane + 64 * k;
    if (e < NTOT) {
      const int r = (e >= NWIN) ? 1 : 0;
      const int m = e - r * NWIN;
      const float pv = p[k];
      if (r == 0) {
        if (better(pv, m, a1_0, j1_0)) { a2_0 = a1_0; j2_0 = j1_0; a1_0 = pv; j1_0 = m; }
        else if (better(pv, m, a2_0, j2_0)) { a2_0 = pv; j2_0 = m; }
      } else {
        if (better(pv, m, a1_1, j1_1)) { a2_1 = a1_1; j2_1 = j1_1; a1_1 = pv; j1_1 = m; }
        else if (better(pv, m, a2_1, j2_1)) { a2_1 = pv; j2_1 = m; }
      }
    }
  }
  #pragma unroll
  for (int off = 32; off > 0; off >>= 1) {
    {
      const float u1 = __shfl_xor(a1_0, off); const int q1 = __shfl_xor(j1_0, off);
      const float u2 = __shfl_xor(a2_0, off); const int q2 = __shfl_xor(j2_0, off);
      if (better(u1, q1, a1_0, j1_0)) {
        float nv2; int ni2;
        if (better(a1_0, j1_0, u2, q2)) { nv2 = a1_0; ni2 = j1_0; }
        else                            { nv2 = u2;   ni2 = q2; }
        a1_0 = u1; j1_0 = q1; a2_0 = nv2; j2_0 = ni2;
      } else if (better(u1, q1, a2_0, j2_0)) { a2_0 = u1; j2_0 = q1; }
    }
    {
      const float u1 = __shfl_xor(a1_1, off); const int q1 = __shfl_xor(j1_1, off);
      const float u2 = __shfl_xor(a2_1, off); const int q2 = __shfl_xor(j2_1, off);
      if (better(u1, q1, a1_1, j1_1)) {
        float nv2; int ni2;
        if (better(a1_1, j1_1, u2, q2)) { nv2 = a1_1; ni2 = j1_1; }
        else                            { nv2 = u2;   ni2 = q2; }
        a1_1 = u1; j1_1 = q1; a2_1 = nv2; j2_1 = ni2;
      } else if (better(u1, q1, a2_1, j2_1)) { a2_1 = u1; j2_1 = q1; }
    }
  }

  const float e10 = __expf(a1_0), e20 = __expf(a2_0);
  const float rs0 = 1.f / (e10 + e20);
  const float w00 = e10 * rs0, w10 = e20 * rs0;
  const bool  fl0 = (a1_0 > 0.1f);
  const float xs00 = (float)(j1_0 % P), ys00 = (float)(j1_0 / P);
  const float xs10 = (float)(j2_0 % P), ys10 = (float)(j2_0 / P);

  const float e11 = __expf(a1_1), e21 = __expf(a2_1);
  const float rs1 = 1.f / (e11 + e21);
  const float w01 = e11 * rs1, w11 = e21 * rs1;
  const bool  fl1 = (a1_1 > 0.1f);
  const float xs01 = (float)(j1_1 % P), ys01 = (float)(j1_1 / P);
  const float xs11 = (float)(j2_1 % P), ys11 = (float)(j2_1 / P);

  #pragma unroll
  for (int k = 0; k < 6; ++k) {
    const int e = lane + 64 * k;
    if (e < NTOT) {
      const int r  = (e >= NWIN) ? 1 : 0;
      const int m  = e - r * NWIN;
      const int dy = m / P;
      const int dx = m - dy * P;
      const bool  fl = r ? fl1 : fl0;
      float val;
      if (fl) {
        const float wA = r ? w01 : w00, wB = r ? w11 : w10;
        const float xA = r ? xs01 : xs00, yA = r ? ys01 : ys00;
        const float xB = r ? xs11 : xs10, yB = r ? ys11 : ys10;
        const float fdx0 = (float)dx - xA, fdy0 = (float)dy - yA;
        const float fdx1 = (float)dx - xB, fdy1 = (float)dy - yB;
        val = wA * __expf(-FOUR_LN2 * (fdx0 * fdx0 + fdy0 * fdy0))
            + wB * __expf(-FOUR_LN2 * (fdx1 * fdx1 + fdy1 * fdy1));
      } else {
        val = p[k];
      }
      const int yy = y + dy - RAD;
      const int xx = x + dx - RAD;
      if ((unsigned)yy < 64u && (unsigned)xx < 64u) {
        const int cls = lab[(size_t)(r * 2 + b) * 4096 + yy * W + xx];
        atomicAdd(&accS[w][cls], val);
      }
    }
  }
  __syncthreads();

  if (t < 4 * NCLS) {
    const int cls = t >> 2;
    const int j   = t & 3;
    const int x0  = (blk * 4) & 63;
    const float sc = (cls == 0) ? 1.0f : 1.15f;
    out[(size_t)(b * NCLS + cls) * HW + y * W + x0 + j] = accS[j][cls] * sc;
  }
}

}  // namespace

extern "C" void kernel_launch(void* const* d_in, const int* in_sizes, int n_in,
                              void* d_out, int out_size, void* d_ws, size_t ws_size,
                              hipStream_t stream) {
  const float* fr = (const float*)d_in[0];   // feats_r
  const float* ft = (const float*)d_in[1];   // feats_t
  const int*   q  = (const int*)d_in[2];     // quantized_r
  float* out = (float*)d_out;
  float* vol = (float*)d_ws;                                   // 11,075,584 B
  int*   lab = (int*)((char*)d_ws + VOLF * sizeof(float));     // +64 KB

  corr_kernel<<<dim3(2 * 2 * 64 * 2), dim3(256), 0, stream>>>(fr, ft, vol, q, lab);
  post_kernel<<<dim3(2 * HW / 4), dim3(256), 0, stream>>>(vol, lab, out);
}